// Round 7
// baseline (682.112 us; speedup 1.0000x reference)
//
#include <hip/hip_runtime.h>
#include <hip/hip_bf16.h>
#include <hip/hip_fp16.h>
#include <math.h>

// Problem constants
#define KN 2048      // num_embeddings (GEMM N)
#define DN 256       // embedding_dim  (GEMM K)
#define NN 32768     // B*H*W          (GEMM M)
#define HW 1024      // H*W
#define XSTR 260     // padded LDS row stride for x tile (floats)

typedef _Float16 half8 __attribute__((ext_vector_type(8)));
typedef float floatx4 __attribute__((ext_vector_type(4)));

// ws layout (bytes):
//   counts    int[2048]     @ 0        (zeroed each call)
//   lossparts float[256]    @ 8192     (zeroed each call)
//   donecnt   int           @ 9216     (zeroed each call)
//   normsq    double[2048]  @ 16384    (zeroed each call; f64 atomic partials)
//   idx       int[32768]    @ 32768
//   Et        f16[1048576]  @ 163840   (2 MB) tile-order, pre-normalized:
//     tile t = nc*8+kh (nc: 128-col group, kh: 32-d group), 8192 halfs:
//     [w:4][s:4][lane:64][j:8], s = {nf0 hi, nf1 hi, nf0 lo, nf1 lo},
//     lane = lg*16+col16, k-in-32 = lg*8+j, col = nc*128+w*32+nf*16+col16

// --------------------------------------- column norm partials (64 blocks)
__global__ __launch_bounds__(256) void k_norm(const float* __restrict__ E,
                                              double* __restrict__ normsq) {
  const int c = ((blockIdx.x & 7) << 8) + threadIdx.x;  // 0..2047
  const int ds = blockIdx.x >> 3;                       // 0..7 (32 d's each)
  const float* p = E + (size_t)(ds * 32) * KN + c;
  double s = 0.0;
#pragma unroll 8
  for (int d = 0; d < 32; ++d) {
    double v = (double)p[(size_t)d * KN];
    s = fma(v, v, s);
  }
  atomicAdd(&normsq[c], s);
}

// --------------------- E -> normalized f16 hi/lo, tile order (see ws map)
__global__ __launch_bounds__(256) void k_convE(const float* __restrict__ E,
                                               const double* __restrict__ normsq,
                                               _Float16* __restrict__ Et) {
  const int c = ((blockIdx.x & 7) << 8) + threadIdx.x;  // 0..2047
  const int dg = blockIdx.x >> 3;                       // 0..31 (8-d groups)
  const int kh = dg >> 2, lg = dg & 3;
  const int nc = c >> 7, w = (c >> 5) & 3, nf = (c >> 4) & 1, col16 = c & 15;
  const int t = nc * 8 + kh;
  double nr = sqrt(normsq[c]);
  if (nr < 1e-12) nr = 1e-12;
  const double inv = 1.0 / nr;
  const size_t base =
      (size_t)t * 8192 + w * 2048 + nf * 512 + (lg * 16 + col16) * 8;
  half8 hv, lv;
#pragma unroll
  for (int j = 0; j < 8; ++j) {
    float v = (float)((double)E[(size_t)(dg * 8 + j) * KN + c] * inv);
    _Float16 h = (_Float16)v;
    hv[j] = h;
    lv[j] = (_Float16)((v - (float)h) * 4096.0f);
  }
  *(half8*)(Et + base) = hv;
  *(half8*)(Et + base + 1024) = lv;  // s_lo = s_hi + 2 -> +1024 halfs
}

// -------------------------------------------------- async global->LDS helper
__device__ __forceinline__ void gload_lds16(const void* g, void* l) {
  __builtin_amdgcn_global_load_lds(
      (const __attribute__((address_space(1))) unsigned int*)g,
      (__attribute__((address_space(3))) unsigned int*)l, 16, 0, 0);
}

// ----------------------------------------------- fused MFMA GEMM^3 + argmax
// grid 1024 x 256 thr (4 waves). Block: 32 rows x 2048 cols. 128 tiles of
// (128 cols x 32 d, hi+lo) = 16 KB; 3 LDS buffers (48 KB -> 3 blocks/CU),
// 2 tiles in flight, counted vmcnt(4) + raw s_barrier per tile.
// Buffer of tile t is t%3; with nc = 3*nc3+ncp, t%3 = (2*ncp+kh)%3 (folds).
#define STAGE(t, buf)                                                        \
  {                                                                          \
    const size_t gb_ = (size_t)(t) * 8192;                                   \
    const int lb_ = (buf) * 16384;                                           \
    _Pragma("unroll") for (int q_ = 0; q_ < 4; ++q_)                         \
        gload_lds16(Et + gb_ + q_ * 2048 + tid * 8,                          \
                    lds + lb_ + q_ * 4096 + tid * 16);                       \
  }

#define ITER(nc, ncp, kh, WAITOP, DO_STAGE)                                  \
  {                                                                          \
    asm volatile(WAITOP ::: "memory");                                       \
    __builtin_amdgcn_s_barrier();                                            \
    __builtin_amdgcn_sched_barrier(0);                                       \
    const int t_ = (nc)*8 + (kh);                                            \
    if (DO_STAGE) { STAGE(t_ + 2, ((2 * (ncp) + (kh) + 2) % 3)); }           \
    const char* wb_ = lds + ((2 * (ncp) + (kh)) % 3) * 16384 + w * 4096;     \
    half8 bh_[2], bl_[2];                                                    \
    bh_[0] = *(const half8*)(wb_ + lane * 16);                               \
    bh_[1] = *(const half8*)(wb_ + 1024 + lane * 16);                        \
    bl_[0] = *(const half8*)(wb_ + 2048 + lane * 16);                        \
    bl_[1] = *(const half8*)(wb_ + 3072 + lane * 16);                        \
    __builtin_amdgcn_s_setprio(1);                                           \
    _Pragma("unroll") for (int mf_ = 0; mf_ < 2; ++mf_)                      \
        _Pragma("unroll") for (int nf_ = 0; nf_ < 2; ++nf_) {                \
      accm[mf_][nf_] = __builtin_amdgcn_mfma_f32_16x16x32_f16(               \
          ah[mf_][(kh)], bh_[nf_], accm[mf_][nf_], 0, 0, 0);                 \
      accc[mf_][nf_] = __builtin_amdgcn_mfma_f32_16x16x32_f16(               \
          ah[mf_][(kh)], bl_[nf_], accc[mf_][nf_], 0, 0, 0);                 \
      accc[mf_][nf_] = __builtin_amdgcn_mfma_f32_16x16x32_f16(               \
          al[mf_][(kh)], bh_[nf_], accc[mf_][nf_], 0, 0, 0);                 \
    }                                                                        \
    __builtin_amdgcn_s_setprio(0);                                           \
  }

#define ZEROACC                                                              \
  {                                                                          \
    _Pragma("unroll") for (int mf_ = 0; mf_ < 2; ++mf_)                      \
        _Pragma("unroll") for (int nf_ = 0; nf_ < 2; ++nf_) {                \
      accm[mf_][nf_] = (floatx4)0.0f;                                        \
      accc[mf_][nf_] = (floatx4)0.0f;                                        \
    }                                                                        \
  }

#define EPILOGUE(nc)                                                         \
  {                                                                          \
    _Pragma("unroll") for (int nf_ = 0; nf_ < 2; ++nf_) {                    \
      const int c_ = (nc)*128 + w * 32 + nf_ * 16 + c16;                     \
      _Pragma("unroll") for (int mf_ = 0; mf_ < 2; ++mf_)                    \
          _Pragma("unroll") for (int r_ = 0; r_ < 4; ++r_) {                 \
        const double s_ = (double)accm[mf_][nf_][r_] +                       \
                          (double)accc[mf_][nf_][r_] * (1.0 / 4096.0);       \
        if (s_ > best[mf_][r_]) { best[mf_][r_] = s_; bidx[mf_][r_] = c_; }  \
      }                                                                      \
    }                                                                        \
  }

#define W4 "s_waitcnt vmcnt(4)"
#define W0 "s_waitcnt vmcnt(0)"

__global__ __launch_bounds__(256, 3) void k_score(
    const float* __restrict__ x, const _Float16* __restrict__ Et,
    int* __restrict__ idx_ws, float* __restrict__ fidx_out,
    int* __restrict__ counts) {
  __shared__ __align__(16) char lds[49152];
  const int tid = threadIdx.x;
  const int lane = tid & 63;
  const int w = tid >> 6;
  const int lg = lane >> 4;
  const int c16 = lane & 15;
  const int rowbase = blockIdx.x * 32;

  // ---- stage x tile (f32) into LDS [32][XSTR] (33,280 B < 48 KB)
  {
    float* xs = (float*)lds;
    const int r = tid & 31;
    const int d0 = tid >> 5;
    const int n = rowbase + r;
    const float* xb = x + (size_t)(n >> 10) * (DN * HW) + (n & 1023);
#pragma unroll
    for (int d = d0; d < DN; d += 8)
      xs[r * XSTR + d] = xb[(size_t)d * HW];
  }
  __syncthreads();

  // ---- build A fragments: row=lane&15 (+16*mf), k = kh*32 + lg*8 + i
  half8 ah[2][8], al[2][8];
  {
    const float* xs = (const float*)lds;
#pragma unroll
    for (int mf = 0; mf < 2; ++mf)
#pragma unroll
      for (int kh = 0; kh < 8; ++kh) {
        const float* p = xs + (mf * 16 + c16) * XSTR + kh * 32 + lg * 8;
        half8 h, l;
#pragma unroll
        for (int i = 0; i < 8; ++i) {
          float v = p[i];
          _Float16 hh = (_Float16)v;
          h[i] = hh;
          l[i] = (_Float16)((v - (float)hh) * 4096.0f);
        }
        ah[mf][kh] = h;
        al[mf][kh] = l;
      }
  }
  __syncthreads();  // all waves done with xs; LDS becomes staging buffers

  double best[2][4];
  int bidx[2][4];
#pragma unroll
  for (int mf = 0; mf < 2; ++mf)
#pragma unroll
    for (int r = 0; r < 4; ++r) { best[mf][r] = -1e300; bidx[mf][r] = 0; }

  floatx4 accm[2][2], accc[2][2];

  // prologue: 2 tiles in flight (8 outstanding loads per thread)
  STAGE(0, 0);
  STAGE(1, 1);

  for (int nc3 = 0; nc3 < 5; ++nc3) {
#pragma unroll
    for (int ncp = 0; ncp < 3; ++ncp) {
      const int nc = nc3 * 3 + ncp;
      ZEROACC;
      ITER(nc, ncp, 0, W4, 1);
      ITER(nc, ncp, 1, W4, 1);
      ITER(nc, ncp, 2, W4, 1);
      ITER(nc, ncp, 3, W4, 1);
      ITER(nc, ncp, 4, W4, 1);
      ITER(nc, ncp, 5, W4, 1);
      ITER(nc, ncp, 6, W4, 1);
      ITER(nc, ncp, 7, W4, 1);
      EPILOGUE(nc);
    }
  }
  // nc = 15 (ncp pattern = 0): last stage targets t+2 = 127 at kh=5
  ZEROACC;
  ITER(15, 0, 0, W4, 1);
  ITER(15, 0, 1, W4, 1);
  ITER(15, 0, 2, W4, 1);
  ITER(15, 0, 3, W4, 1);
  ITER(15, 0, 4, W4, 1);
  ITER(15, 0, 5, W4, 1);
  ITER(15, 0, 6, W4, 0);
  ITER(15, 0, 7, W0, 0);
  EPILOGUE(15);

  // ---- final reduction: 64 (wave, col-lane) entries per row
  __syncthreads();
  double* redD = (double*)lds;       // 32*64 doubles = 16 KB
  int* redI = (int*)(lds + 16384);   // 8 KB
  const int ent = w * 16 + c16;
#pragma unroll
  for (int mf = 0; mf < 2; ++mf)
#pragma unroll
    for (int r = 0; r < 4; ++r) {
      const int row = mf * 16 + lg * 4 + r;
      redD[row * 64 + ent] = best[mf][r];
      redI[row * 64 + ent] = bidx[mf][r];
    }
  __syncthreads();
  if (tid < 32) {
    double bd = -1e300;
    int bi = 1 << 30;
    for (int e = 0; e < 64; ++e) {
      double dv = redD[tid * 64 + e];
      int iv = redI[tid * 64 + e];
      if (dv > bd || (dv == bd && iv < bi)) { bd = dv; bi = iv; }
    }
    const int n = rowbase + tid;
    idx_ws[n] = bi;
    fidx_out[n] = (float)bi;
    atomicAdd(&counts[bi], 1);
  }
}

// --------------------- gather + quantize + loss (+ fused final reduction)
__global__ __launch_bounds__(256) void k_quant(const float* __restrict__ x,
                                               const float* __restrict__ E,
                                               const int* __restrict__ idx,
                                               float* __restrict__ out,
                                               float* __restrict__ lossparts,
                                               const int* __restrict__ counts,
                                               int* __restrict__ donecnt) {
  const int T = blockIdx.x * 256 + threadIdx.x;
  const int w4 = T & 7;
  int rest = T >> 3;
  const int h = rest & 31;
  rest >>= 5;
  const int d = rest & 255;
  const int b = rest >> 8;
  const int n = b * 1024 + h * 32 + w4 * 4;
  const int4 iv = *(const int4*)(idx + n);
  const size_t xoff = ((size_t)(b * 256 + d) << 10) + h * 32 + w4 * 4;
  const float4 xv = *(const float4*)(x + xoff);
  const float* Er = E + (size_t)d * KN;
  float4 q;
  q.x = Er[iv.x];
  q.y = Er[iv.y];
  q.z = Er[iv.z];
  q.w = Er[iv.w];
  *(float4*)(out + xoff) = q;
  const float dx = xv.x - q.x, dy = xv.y - q.y, dz = xv.z - q.z, dw = xv.w - q.w;
  float s = dx * dx + dy * dy + dz * dz + dw * dw;
#pragma unroll
  for (int off = 32; off > 0; off >>= 1) s += __shfl_down(s, off, 64);
  __shared__ float red[4];
  const int tid = threadIdx.x;
  const int lane = tid & 63, wv = tid >> 6;
  if (lane == 0) red[wv] = s;
  __syncthreads();
  __shared__ int lastFlag;
  if (tid == 0) {
    atomicAdd(&lossparts[blockIdx.x & 255], red[0] + red[1] + red[2] + red[3]);
    __threadfence();
    lastFlag = (atomicAdd(donecnt, 1) == 8191);
  }
  __syncthreads();
  if (!lastFlag) return;
  __threadfence();

  // ---- last block: entropy over counts + loss sum over lossparts
  __shared__ double redE[256];
  __shared__ double redL[256];
  double t = 0.0;
  for (int u = tid; u < KN; u += 256) {
    float p = (float)counts[u] * (1.0f / 32768.0f);
    t += (double)(p * logf(p + 1e-10f));
  }
  redE[tid] = t;
  redL[tid] = (double)atomicAdd(&lossparts[tid], 0.0f);  // coherent read
  __syncthreads();
  for (int s2 = 128; s2 > 0; s2 >>= 1) {
    if (tid < s2) {
      redE[tid] += redE[tid + s2];
      redL[tid] += redL[tid + s2];
    }
    __syncthreads();
  }
  if (tid == 0) {
    float L = (float)(redL[0] * (1.0 / 8388608.0));
    out[8388608] = L;  // dictionary_loss
    out[8388609] = L;  // commitment_loss (identical in forward)
    out[8388610] = (float)redE[0];
  }
}

extern "C" void kernel_launch(void* const* d_in, const int* in_sizes, int n_in,
                              void* d_out, int out_size, void* d_ws, size_t ws_size,
                              hipStream_t stream) {
  const float* x = (const float*)d_in[0];
  const float* E = (const float*)d_in[1];
  float* out = (float*)d_out;
  char* ws = (char*)d_ws;
  int* counts = (int*)ws;
  float* lossparts = (float*)(ws + 8192);
  int* donecnt = (int*)(ws + 9216);
  double* normsq = (double*)(ws + 16384);
  int* idx = (int*)(ws + 32768);
  _Float16* Et = (_Float16*)(ws + 163840);

  hipMemsetAsync(ws, 0, 32768, stream);  // counts+lossparts+donecnt+normsq
  k_norm<<<64, 256, 0, stream>>>(E, normsq);
  k_convE<<<256, 256, 0, stream>>>(E, normsq, Et);
  k_score<<<NN / 32, 256, 0, stream>>>(x, Et, idx, out + 8388611, counts);
  k_quant<<<(NN * DN / 4) / 256, 256, 0, stream>>>(x, E, idx, out, lossparts,
                                                   counts, donecnt);
}

// Round 8
// 219.145 us; speedup vs baseline: 3.1126x; 3.1126x over previous
//
#include <hip/hip_runtime.h>
#include <hip/hip_bf16.h>
#include <hip/hip_fp16.h>
#include <math.h>

// Problem constants
#define KN 2048      // num_embeddings (GEMM N)
#define DN 256       // embedding_dim  (GEMM K)
#define NN 32768     // B*H*W          (GEMM M)
#define HW 1024      // H*W
#define XSTR 260     // padded LDS row stride for x tile (floats)

typedef _Float16 half8 __attribute__((ext_vector_type(8)));
typedef float floatx4 __attribute__((ext_vector_type(4)));

// ws layout (bytes):
//   counts    int[2048]     @ 0        (zeroed each call)
//   lossparts float[256]    @ 8192     (zeroed each call)
//   normsq    double[2048]  @ 16384    (zeroed each call; f64 atomic partials)
//   idx       int[32768]    @ 32768
//   Et        f16[1048576]  @ 163840   (2 MB) tile-order, pre-normalized:
//     tile t = nc*8+kh (nc: 128-col group, kh: 32-d group), 8192 halfs:
//     [w:4][s:4][lane:64][j:8], s = {nf0 hi, nf1 hi, nf0 lo, nf1 lo},
//     lane = lg*16+col16, k-in-32 = lg*8+j, col = nc*128+w*32+nf*16+col16

// --------------------------------------- column norm partials (64 blocks)
__global__ __launch_bounds__(256) void k_norm(const float* __restrict__ E,
                                              double* __restrict__ normsq) {
  const int c = ((blockIdx.x & 7) << 8) + threadIdx.x;  // 0..2047
  const int ds = blockIdx.x >> 3;                       // 0..7 (32 d's each)
  const float* p = E + (size_t)(ds * 32) * KN + c;
  double s = 0.0;
#pragma unroll 8
  for (int d = 0; d < 32; ++d) {
    double v = (double)p[(size_t)d * KN];
    s = fma(v, v, s);
  }
  atomicAdd(&normsq[c], s);
}

// --------------------- E -> normalized f16 hi/lo, tile order (see ws map)
__global__ __launch_bounds__(256) void k_convE(const float* __restrict__ E,
                                               const double* __restrict__ normsq,
                                               _Float16* __restrict__ Et) {
  const int c = ((blockIdx.x & 7) << 8) + threadIdx.x;  // 0..2047
  const int dg = blockIdx.x >> 3;                       // 0..31 (8-d groups)
  const int kh = dg >> 2, lg = dg & 3;
  const int nc = c >> 7, w = (c >> 5) & 3, nf = (c >> 4) & 1, col16 = c & 15;
  const int t = nc * 8 + kh;
  double nr = sqrt(normsq[c]);
  if (nr < 1e-12) nr = 1e-12;
  const double inv = 1.0 / nr;
  const size_t base =
      (size_t)t * 8192 + w * 2048 + nf * 512 + (lg * 16 + col16) * 8;
  half8 hv, lv;
#pragma unroll
  for (int j = 0; j < 8; ++j) {
    float v = (float)((double)E[(size_t)(dg * 8 + j) * KN + c] * inv);
    _Float16 h = (_Float16)v;
    hv[j] = h;
    lv[j] = (_Float16)((v - (float)h) * 4096.0f);
  }
  *(half8*)(Et + base) = hv;
  *(half8*)(Et + base + 1024) = lv;  // s_lo = s_hi + 2 -> +1024 halfs
}

// -------------------------------------------------- async global->LDS helper
__device__ __forceinline__ void gload_lds16(const void* g, void* l) {
  __builtin_amdgcn_global_load_lds(
      (const __attribute__((address_space(1))) unsigned int*)g,
      (__attribute__((address_space(3))) unsigned int*)l, 16, 0, 0);
}

// ----------------------------------------------- fused MFMA GEMM^3 + argmax
// grid 1024 x 256 thr (4 waves). Block: 32 rows x 2048 cols. 128 tiles of
// (128 cols x 32 d, hi+lo) = 16 KB; 3 LDS buffers (48 KB -> 3 blocks/CU by
// LDS cap; VGPR ~120 -> 4 waves/SIMD, NOT the limiter), 2 tiles in flight,
// counted vmcnt(4) + raw s_barrier per tile.
// NOTE: launch_bounds second arg MUST stay 2 — (256,3) cut the VGPR budget
// to 84 and spilled the A fragments (R7: 363 us, 535 MB scratch fetch).
// Buffer of tile t is t%3; with nc = 3*nc3+ncp, t%3 = (2*ncp+kh)%3 (folds).
#define STAGE(t, buf)                                                        \
  {                                                                          \
    const size_t gb_ = (size_t)(t) * 8192;                                   \
    const int lb_ = (buf) * 16384;                                           \
    _Pragma("unroll") for (int q_ = 0; q_ < 4; ++q_)                         \
        gload_lds16(Et + gb_ + q_ * 2048 + tid * 8,                          \
                    lds + lb_ + q_ * 4096 + tid * 16);                       \
  }

#define ITER(nc, ncp, kh, WAITOP, DO_STAGE)                                  \
  {                                                                          \
    asm volatile(WAITOP ::: "memory");                                       \
    __builtin_amdgcn_s_barrier();                                            \
    __builtin_amdgcn_sched_barrier(0);                                       \
    const int t_ = (nc)*8 + (kh);                                            \
    if (DO_STAGE) { STAGE(t_ + 2, ((2 * (ncp) + (kh) + 2) % 3)); }           \
    const char* wb_ = lds + ((2 * (ncp) + (kh)) % 3) * 16384 + w * 4096;     \
    half8 bh_[2], bl_[2];                                                    \
    bh_[0] = *(const half8*)(wb_ + lane * 16);                               \
    bh_[1] = *(const half8*)(wb_ + 1024 + lane * 16);                        \
    bl_[0] = *(const half8*)(wb_ + 2048 + lane * 16);                        \
    bl_[1] = *(const half8*)(wb_ + 3072 + lane * 16);                        \
    __builtin_amdgcn_s_setprio(1);                                           \
    _Pragma("unroll") for (int mf_ = 0; mf_ < 2; ++mf_)                      \
        _Pragma("unroll") for (int nf_ = 0; nf_ < 2; ++nf_) {                \
      accm[mf_][nf_] = __builtin_amdgcn_mfma_f32_16x16x32_f16(               \
          ah[mf_][(kh)], bh_[nf_], accm[mf_][nf_], 0, 0, 0);                 \
      accc[mf_][nf_] = __builtin_amdgcn_mfma_f32_16x16x32_f16(               \
          ah[mf_][(kh)], bl_[nf_], accc[mf_][nf_], 0, 0, 0);                 \
      accc[mf_][nf_] = __builtin_amdgcn_mfma_f32_16x16x32_f16(               \
          al[mf_][(kh)], bh_[nf_], accc[mf_][nf_], 0, 0, 0);                 \
    }                                                                        \
    __builtin_amdgcn_s_setprio(0);                                           \
  }

#define ZEROACC                                                              \
  {                                                                          \
    _Pragma("unroll") for (int mf_ = 0; mf_ < 2; ++mf_)                      \
        _Pragma("unroll") for (int nf_ = 0; nf_ < 2; ++nf_) {                \
      accm[mf_][nf_] = (floatx4)0.0f;                                        \
      accc[mf_][nf_] = (floatx4)0.0f;                                        \
    }                                                                        \
  }

#define EPILOGUE(nc)                                                         \
  {                                                                          \
    _Pragma("unroll") for (int nf_ = 0; nf_ < 2; ++nf_) {                    \
      const int c_ = (nc)*128 + w * 32 + nf_ * 16 + c16;                     \
      _Pragma("unroll") for (int mf_ = 0; mf_ < 2; ++mf_)                    \
          _Pragma("unroll") for (int r_ = 0; r_ < 4; ++r_) {                 \
        const double s_ = (double)accm[mf_][nf_][r_] +                       \
                          (double)accc[mf_][nf_][r_] * (1.0 / 4096.0);       \
        if (s_ > best[mf_][r_]) { best[mf_][r_] = s_; bidx[mf_][r_] = c_; }  \
      }                                                                      \
    }                                                                        \
  }

#define W4 "s_waitcnt vmcnt(4)"
#define W0 "s_waitcnt vmcnt(0)"

__global__ __launch_bounds__(256, 2) void k_score(
    const float* __restrict__ x, const _Float16* __restrict__ Et,
    int* __restrict__ idx_ws, float* __restrict__ fidx_out,
    int* __restrict__ counts) {
  __shared__ __align__(16) char lds[49152];
  const int tid = threadIdx.x;
  const int lane = tid & 63;
  const int w = tid >> 6;
  const int lg = lane >> 4;
  const int c16 = lane & 15;
  const int rowbase = blockIdx.x * 32;

  // ---- stage x tile (f32) into LDS [32][XSTR] (33,280 B < 48 KB)
  {
    float* xs = (float*)lds;
    const int r = tid & 31;
    const int d0 = tid >> 5;
    const int n = rowbase + r;
    const float* xb = x + (size_t)(n >> 10) * (DN * HW) + (n & 1023);
#pragma unroll
    for (int d = d0; d < DN; d += 8)
      xs[r * XSTR + d] = xb[(size_t)d * HW];
  }
  __syncthreads();

  // ---- build A fragments: row=lane&15 (+16*mf), k = kh*32 + lg*8 + i
  half8 ah[2][8], al[2][8];
  {
    const float* xs = (const float*)lds;
#pragma unroll
    for (int mf = 0; mf < 2; ++mf)
#pragma unroll
      for (int kh = 0; kh < 8; ++kh) {
        const float* p = xs + (mf * 16 + c16) * XSTR + kh * 32 + lg * 8;
        half8 h, l;
#pragma unroll
        for (int i = 0; i < 8; ++i) {
          float v = p[i];
          _Float16 hh = (_Float16)v;
          h[i] = hh;
          l[i] = (_Float16)((v - (float)hh) * 4096.0f);
        }
        ah[mf][kh] = h;
        al[mf][kh] = l;
      }
  }
  __syncthreads();  // all waves done with xs; LDS becomes staging buffers

  double best[2][4];
  int bidx[2][4];
#pragma unroll
  for (int mf = 0; mf < 2; ++mf)
#pragma unroll
    for (int r = 0; r < 4; ++r) { best[mf][r] = -1e300; bidx[mf][r] = 0; }

  floatx4 accm[2][2], accc[2][2];

  // prologue: 2 tiles in flight (8 outstanding loads per thread)
  STAGE(0, 0);
  STAGE(1, 1);

  for (int nc3 = 0; nc3 < 5; ++nc3) {
#pragma unroll
    for (int ncp = 0; ncp < 3; ++ncp) {
      const int nc = nc3 * 3 + ncp;
      ZEROACC;
      ITER(nc, ncp, 0, W4, 1);
      ITER(nc, ncp, 1, W4, 1);
      ITER(nc, ncp, 2, W4, 1);
      ITER(nc, ncp, 3, W4, 1);
      ITER(nc, ncp, 4, W4, 1);
      ITER(nc, ncp, 5, W4, 1);
      ITER(nc, ncp, 6, W4, 1);
      ITER(nc, ncp, 7, W4, 1);
      EPILOGUE(nc);
    }
  }
  // nc = 15 (ncp pattern = 0): last stage targets t+2 = 127 at kh=5
  ZEROACC;
  ITER(15, 0, 0, W4, 1);
  ITER(15, 0, 1, W4, 1);
  ITER(15, 0, 2, W4, 1);
  ITER(15, 0, 3, W4, 1);
  ITER(15, 0, 4, W4, 1);
  ITER(15, 0, 5, W4, 1);
  ITER(15, 0, 6, W4, 0);
  ITER(15, 0, 7, W0, 0);
  EPILOGUE(15);

  // ---- final reduction: 64 (wave, col-lane) entries per row
  __syncthreads();
  double* redD = (double*)lds;       // 32*64 doubles = 16 KB
  int* redI = (int*)(lds + 16384);   // 8 KB
  const int ent = w * 16 + c16;
#pragma unroll
  for (int mf = 0; mf < 2; ++mf)
#pragma unroll
    for (int r = 0; r < 4; ++r) {
      const int row = mf * 16 + lg * 4 + r;
      redD[row * 64 + ent] = best[mf][r];
      redI[row * 64 + ent] = bidx[mf][r];
    }
  __syncthreads();
  if (tid < 32) {
    double bd = -1e300;
    int bi = 1 << 30;
    for (int e = 0; e < 64; ++e) {
      double dv = redD[tid * 64 + e];
      int iv = redI[tid * 64 + e];
      if (dv > bd || (dv == bd && iv < bi)) { bd = dv; bi = iv; }
    }
    const int n = rowbase + tid;
    idx_ws[n] = bi;
    fidx_out[n] = (float)bi;
    atomicAdd(&counts[bi], 1);
  }
}

// ------------------------------------------------- gather + quantize + loss
__global__ __launch_bounds__(256) void k_quant(const float* __restrict__ x,
                                               const float* __restrict__ E,
                                               const int* __restrict__ idx,
                                               float* __restrict__ out,
                                               float* __restrict__ lossparts) {
  const int T = blockIdx.x * 256 + threadIdx.x;
  const int w4 = T & 7;
  int rest = T >> 3;
  const int h = rest & 31;
  rest >>= 5;
  const int d = rest & 255;
  const int b = rest >> 8;
  const int n = b * 1024 + h * 32 + w4 * 4;
  const int4 iv = *(const int4*)(idx + n);
  const size_t xoff = ((size_t)(b * 256 + d) << 10) + h * 32 + w4 * 4;
  const float4 xv = *(const float4*)(x + xoff);
  const float* Er = E + (size_t)d * KN;
  float4 q;
  q.x = Er[iv.x];
  q.y = Er[iv.y];
  q.z = Er[iv.z];
  q.w = Er[iv.w];
  *(float4*)(out + xoff) = q;
  const float dx = xv.x - q.x, dy = xv.y - q.y, dz = xv.z - q.z, dw = xv.w - q.w;
  float s = dx * dx + dy * dy + dz * dz + dw * dw;
#pragma unroll
  for (int off = 32; off > 0; off >>= 1) s += __shfl_down(s, off, 64);
  __shared__ float red[4];
  const int lane = threadIdx.x & 63, wv = threadIdx.x >> 6;
  if (lane == 0) red[wv] = s;
  __syncthreads();
  if (threadIdx.x == 0)
    atomicAdd(&lossparts[blockIdx.x & 255], red[0] + red[1] + red[2] + red[3]);
}

// -------------------------------------------------------- losses + entropy
__global__ __launch_bounds__(256) void k_final(const int* __restrict__ counts,
                                               const float* __restrict__ lossparts,
                                               float* __restrict__ out) {
  __shared__ double redE[256];
  __shared__ double redL[256];
  const int tid = threadIdx.x;
  double t = 0.0;
  for (int u = tid; u < KN; u += 256) {
    float p = (float)counts[u] * (1.0f / 32768.0f);
    t += (double)(p * logf(p + 1e-10f));
  }
  redE[tid] = t;
  redL[tid] = (double)lossparts[tid];
  __syncthreads();
  for (int s2 = 128; s2 > 0; s2 >>= 1) {
    if (tid < s2) {
      redE[tid] += redE[tid + s2];
      redL[tid] += redL[tid + s2];
    }
    __syncthreads();
  }
  if (tid == 0) {
    float L = (float)(redL[0] * (1.0 / 8388608.0));
    out[8388608] = L;  // dictionary_loss
    out[8388609] = L;  // commitment_loss (identical in forward)
    out[8388610] = (float)redE[0];
  }
}

extern "C" void kernel_launch(void* const* d_in, const int* in_sizes, int n_in,
                              void* d_out, int out_size, void* d_ws, size_t ws_size,
                              hipStream_t stream) {
  const float* x = (const float*)d_in[0];
  const float* E = (const float*)d_in[1];
  float* out = (float*)d_out;
  char* ws = (char*)d_ws;
  int* counts = (int*)ws;
  float* lossparts = (float*)(ws + 8192);
  double* normsq = (double*)(ws + 16384);
  int* idx = (int*)(ws + 32768);
  _Float16* Et = (_Float16*)(ws + 163840);

  hipMemsetAsync(ws, 0, 32768, stream);  // counts + lossparts + normsq
  k_norm<<<64, 256, 0, stream>>>(E, normsq);
  k_convE<<<256, 256, 0, stream>>>(E, normsq, Et);
  k_score<<<NN / 32, 256, 0, stream>>>(x, Et, idx, out + 8388611, counts);
  k_quant<<<(NN * DN / 4) / 256, 256, 0, stream>>>(x, E, idx, out, lossparts);
  k_final<<<1, 256, 0, stream>>>(counts, lossparts, out);
}

// Round 9
// 209.582 us; speedup vs baseline: 3.2546x; 1.0456x over previous
//
#include <hip/hip_runtime.h>
#include <hip/hip_bf16.h>
#include <hip/hip_fp16.h>
#include <math.h>

// Problem constants
#define KN 2048      // num_embeddings (GEMM N)
#define DN 256       // embedding_dim  (GEMM K)
#define NN 32768     // B*H*W          (GEMM M)
#define HW 1024      // H*W
#define XSTR 260     // padded LDS row stride for x tile (floats)

typedef _Float16 half8 __attribute__((ext_vector_type(8)));
typedef float floatx4 __attribute__((ext_vector_type(4)));

// ws layout (bytes):
//   counts    int[2048]     @ 0        (zeroed each call)
//   lossparts float[256]    @ 8192     (zeroed each call)
//   normsq    double[2048]  @ 16384    (zeroed each call; f64 atomic partials)
//   idx       int[32768]    @ 32768
//   Et        f16[1048576]  @ 163840   (2 MB; fits each XCD L2) tile-order,
//     pre-normalized: tile t = nc*8+kh, 8192 halfs:
//     [w:4][s:4][lane:64][j:8], s = {nf0 hi, nf1 hi, nf0 lo, nf1 lo},
//     lane = lg*16+col16, k-in-32 = lg*8+j, col = nc*128+w*32+nf*16+col16

// --------------------------------------- column norm partials (64 blocks)
__global__ __launch_bounds__(256) void k_norm(const float* __restrict__ E,
                                              double* __restrict__ normsq) {
  const int c = ((blockIdx.x & 7) << 8) + threadIdx.x;  // 0..2047
  const int ds = blockIdx.x >> 3;                       // 0..7 (32 d's each)
  const float* p = E + (size_t)(ds * 32) * KN + c;
  double s = 0.0;
#pragma unroll 8
  for (int d = 0; d < 32; ++d) {
    double v = (double)p[(size_t)d * KN];
    s = fma(v, v, s);
  }
  atomicAdd(&normsq[c], s);
}

// --------------------- E -> normalized f16 hi/lo, tile order (see ws map)
__global__ __launch_bounds__(256) void k_convE(const float* __restrict__ E,
                                               const double* __restrict__ normsq,
                                               _Float16* __restrict__ Et) {
  const int c = ((blockIdx.x & 7) << 8) + threadIdx.x;  // 0..2047
  const int dg = blockIdx.x >> 3;                       // 0..31 (8-d groups)
  const int kh = dg >> 2, lg = dg & 3;
  const int nc = c >> 7, w = (c >> 5) & 3, nf = (c >> 4) & 1, col16 = c & 15;
  const int t = nc * 8 + kh;
  double nr = sqrt(normsq[c]);
  if (nr < 1e-12) nr = 1e-12;
  const double inv = 1.0 / nr;
  const size_t base =
      (size_t)t * 8192 + w * 2048 + nf * 512 + (lg * 16 + col16) * 8;
  half8 hv, lv;
#pragma unroll
  for (int j = 0; j < 8; ++j) {
    float v = (float)((double)E[(size_t)(dg * 8 + j) * KN + c] * inv);
    _Float16 h = (_Float16)v;
    hv[j] = h;
    lv[j] = (_Float16)((v - (float)h) * 4096.0f);
  }
  *(half8*)(Et + base) = hv;
  *(half8*)(Et + base + 1024) = lv;  // s_lo = s_hi + 2 -> +1024 halfs
}

// ----------------------------------------------- fused MFMA GEMM^3 + argmax
// grid 1024 x 256 thr (4 waves). Block: 32 rows x 2048 cols.
// B fragments load GLOBAL -> REGISTER directly (Et is L2-resident, 2 MB per
// XCD L2): no LDS, no barriers in the main loop. 2-deep software pipeline
// (b0/b1); compiler inserts counted vmcnt for register loads.
// A (x hi/lo) fully register-resident (128 VGPR-equiv).
// waves_per_eu(2,2) pins the budget to 256 regs/lane — R4/R7 spilled because
// the compiler chose a 4-wave budget (128/84 VGPR) for this ~226-reg kernel.

#define LOADB(buf, t)                                                        \
  {                                                                          \
    const _Float16* p_ = bbase + (size_t)(t) * 8192;                         \
    buf[0] = *(const half8*)(p_);                                            \
    buf[1] = *(const half8*)(p_ + 512);                                      \
    buf[2] = *(const half8*)(p_ + 1024);                                     \
    buf[3] = *(const half8*)(p_ + 1536);                                     \
  }

#define COMP(kh, buf)                                                        \
  {                                                                          \
    __builtin_amdgcn_s_setprio(1);                                           \
    _Pragma("unroll") for (int mf_ = 0; mf_ < 2; ++mf_) {                    \
      accm[mf_][0] = __builtin_amdgcn_mfma_f32_16x16x32_f16(                 \
          ah[mf_][(kh)], buf[0], accm[mf_][0], 0, 0, 0);                     \
      accm[mf_][1] = __builtin_amdgcn_mfma_f32_16x16x32_f16(                 \
          ah[mf_][(kh)], buf[1], accm[mf_][1], 0, 0, 0);                     \
      accc[mf_][0] = __builtin_amdgcn_mfma_f32_16x16x32_f16(                 \
          ah[mf_][(kh)], buf[2], accc[mf_][0], 0, 0, 0);                     \
      accc[mf_][1] = __builtin_amdgcn_mfma_f32_16x16x32_f16(                 \
          ah[mf_][(kh)], buf[3], accc[mf_][1], 0, 0, 0);                     \
      accc[mf_][0] = __builtin_amdgcn_mfma_f32_16x16x32_f16(                 \
          al[mf_][(kh)], buf[0], accc[mf_][0], 0, 0, 0);                     \
      accc[mf_][1] = __builtin_amdgcn_mfma_f32_16x16x32_f16(                 \
          al[mf_][(kh)], buf[1], accc[mf_][1], 0, 0, 0);                     \
    }                                                                        \
    __builtin_amdgcn_s_setprio(0);                                           \
  }

#define ITERX(kh, BUF, DOLOAD, tp2)                                          \
  {                                                                          \
    COMP(kh, BUF);                                                           \
    if (DOLOAD) { LOADB(BUF, tp2); }                                         \
  }

#define ZEROACC                                                              \
  {                                                                          \
    _Pragma("unroll") for (int mf_ = 0; mf_ < 2; ++mf_)                      \
        _Pragma("unroll") for (int nf_ = 0; nf_ < 2; ++nf_) {                \
      accm[mf_][nf_] = (floatx4)0.0f;                                        \
      accc[mf_][nf_] = (floatx4)0.0f;                                        \
    }                                                                        \
  }

#define EPILOGUE(nc)                                                         \
  {                                                                          \
    _Pragma("unroll") for (int nf_ = 0; nf_ < 2; ++nf_) {                    \
      const int c_ = (nc)*128 + w * 32 + nf_ * 16 + c16;                     \
      _Pragma("unroll") for (int mf_ = 0; mf_ < 2; ++mf_)                    \
          _Pragma("unroll") for (int r_ = 0; r_ < 4; ++r_) {                 \
        const double s_ = (double)accm[mf_][nf_][r_] +                       \
                          (double)accc[mf_][nf_][r_] * (1.0 / 4096.0);       \
        if (s_ > best[mf_][r_]) { best[mf_][r_] = s_; bidx[mf_][r_] = c_; }  \
      }                                                                      \
    }                                                                        \
  }

__global__ __launch_bounds__(256, 2)
__attribute__((amdgpu_waves_per_eu(2, 2))) void k_score(
    const float* __restrict__ x, const _Float16* __restrict__ Et,
    int* __restrict__ idx_ws, float* __restrict__ fidx_out,
    int* __restrict__ counts) {
  __shared__ __align__(16) char lds[33280];
  const int tid = threadIdx.x;
  const int lane = tid & 63;
  const int w = tid >> 6;
  const int lg = lane >> 4;
  const int c16 = lane & 15;
  const int rowbase = blockIdx.x * 32;

  // ---- stage x tile (f32) into LDS [32][XSTR]
  {
    float* xs = (float*)lds;
    const int r = tid & 31;
    const int d0 = tid >> 5;
    const int n = rowbase + r;
    const float* xb = x + (size_t)(n >> 10) * (DN * HW) + (n & 1023);
#pragma unroll
    for (int d = d0; d < DN; d += 8)
      xs[r * XSTR + d] = xb[(size_t)d * HW];
  }
  __syncthreads();

  // ---- build A fragments: row=lane&15 (+16*mf), k = kh*32 + lg*8 + i
  half8 ah[2][8], al[2][8];
  {
    const float* xs = (const float*)lds;
#pragma unroll
    for (int mf = 0; mf < 2; ++mf)
#pragma unroll
      for (int kh = 0; kh < 8; ++kh) {
        const float* p = xs + (mf * 16 + c16) * XSTR + kh * 32 + lg * 8;
        half8 h, l;
#pragma unroll
        for (int i = 0; i < 8; ++i) {
          float v = p[i];
          _Float16 hh = (_Float16)v;
          h[i] = hh;
          l[i] = (_Float16)((v - (float)hh) * 4096.0f);
        }
        ah[mf][kh] = h;
        al[mf][kh] = l;
      }
  }

  double best[2][4];
  int bidx[2][4];
#pragma unroll
  for (int mf = 0; mf < 2; ++mf)
#pragma unroll
    for (int r = 0; r < 4; ++r) { best[mf][r] = -1e300; bidx[mf][r] = 0; }

  floatx4 accm[2][2], accc[2][2];
  half8 b0[4], b1[4];
  const _Float16* bbase = Et + w * 2048 + lane * 8;

  LOADB(b0, 0);
  LOADB(b1, 1);

  for (int nc = 0; nc < 15; ++nc) {
    const int t0 = nc * 8;
    ZEROACC;
    ITERX(0, b0, 1, t0 + 2);
    ITERX(1, b1, 1, t0 + 3);
    ITERX(2, b0, 1, t0 + 4);
    ITERX(3, b1, 1, t0 + 5);
    ITERX(4, b0, 1, t0 + 6);
    ITERX(5, b1, 1, t0 + 7);
    ITERX(6, b0, 1, t0 + 8);
    ITERX(7, b1, 1, t0 + 9);
    EPILOGUE(nc);
  }
  // nc = 15: last loads issued at kh=5 (tile 127); kh 6,7 consume b0,b1
  ZEROACC;
  ITERX(0, b0, 1, 122);
  ITERX(1, b1, 1, 123);
  ITERX(2, b0, 1, 124);
  ITERX(3, b1, 1, 125);
  ITERX(4, b0, 1, 126);
  ITERX(5, b1, 1, 127);
  ITERX(6, b0, 0, 0);
  ITERX(7, b1, 0, 0);
  EPILOGUE(15);

  // ---- final reduction: 64 (wave, col-lane) entries per row
  __syncthreads();  // xs region reuse
  double* redD = (double*)lds;       // 32*64 doubles = 16 KB
  int* redI = (int*)(lds + 16384);   // 8 KB
  const int ent = w * 16 + c16;
#pragma unroll
  for (int mf = 0; mf < 2; ++mf)
#pragma unroll
    for (int r = 0; r < 4; ++r) {
      const int row = mf * 16 + lg * 4 + r;
      redD[row * 64 + ent] = best[mf][r];
      redI[row * 64 + ent] = bidx[mf][r];
    }
  __syncthreads();
  if (tid < 32) {
    double bd = -1e300;
    int bi = 1 << 30;
    for (int e = 0; e < 64; ++e) {
      double dv = redD[tid * 64 + e];
      int iv = redI[tid * 64 + e];
      if (dv > bd || (dv == bd && iv < bi)) { bd = dv; bi = iv; }
    }
    const int n = rowbase + tid;
    idx_ws[n] = bi;
    fidx_out[n] = (float)bi;
    atomicAdd(&counts[bi], 1);
  }
}

// ------------------------------------------------- gather + quantize + loss
__global__ __launch_bounds__(256) void k_quant(const float* __restrict__ x,
                                               const float* __restrict__ E,
                                               const int* __restrict__ idx,
                                               float* __restrict__ out,
                                               float* __restrict__ lossparts) {
  const int T = blockIdx.x * 256 + threadIdx.x;
  const int w4 = T & 7;
  int rest = T >> 3;
  const int h = rest & 31;
  rest >>= 5;
  const int d = rest & 255;
  const int b = rest >> 8;
  const int n = b * 1024 + h * 32 + w4 * 4;
  const int4 iv = *(const int4*)(idx + n);
  const size_t xoff = ((size_t)(b * 256 + d) << 10) + h * 32 + w4 * 4;
  const float4 xv = *(const float4*)(x + xoff);
  const float* Er = E + (size_t)d * KN;
  float4 q;
  q.x = Er[iv.x];
  q.y = Er[iv.y];
  q.z = Er[iv.z];
  q.w = Er[iv.w];
  *(float4*)(out + xoff) = q;
  const float dx = xv.x - q.x, dy = xv.y - q.y, dz = xv.z - q.z, dw = xv.w - q.w;
  float s = dx * dx + dy * dy + dz * dz + dw * dw;
#pragma unroll
  for (int off = 32; off > 0; off >>= 1) s += __shfl_down(s, off, 64);
  __shared__ float red[4];
  const int lane = threadIdx.x & 63, wv = threadIdx.x >> 6;
  if (lane == 0) red[wv] = s;
  __syncthreads();
  if (threadIdx.x == 0)
    atomicAdd(&lossparts[blockIdx.x & 255], red[0] + red[1] + red[2] + red[3]);
}

// -------------------------------------------------------- losses + entropy
__global__ __launch_bounds__(256) void k_final(const int* __restrict__ counts,
                                               const float* __restrict__ lossparts,
                                               float* __restrict__ out) {
  __shared__ double redE[256];
  __shared__ double redL[256];
  const int tid = threadIdx.x;
  double t = 0.0;
  for (int u = tid; u < KN; u += 256) {
    float p = (float)counts[u] * (1.0f / 32768.0f);
    t += (double)(p * logf(p + 1e-10f));
  }
  redE[tid] = t;
  redL[tid] = (double)lossparts[tid];
  __syncthreads();
  for (int s2 = 128; s2 > 0; s2 >>= 1) {
    if (tid < s2) {
      redE[tid] += redE[tid + s2];
      redL[tid] += redL[tid + s2];
    }
    __syncthreads();
  }
  if (tid == 0) {
    float L = (float)(redL[0] * (1.0 / 8388608.0));
    out[8388608] = L;  // dictionary_loss
    out[8388609] = L;  // commitment_loss (identical in forward)
    out[8388610] = (float)redE[0];
  }
}

extern "C" void kernel_launch(void* const* d_in, const int* in_sizes, int n_in,
                              void* d_out, int out_size, void* d_ws, size_t ws_size,
                              hipStream_t stream) {
  const float* x = (const float*)d_in[0];
  const float* E = (const float*)d_in[1];
  float* out = (float*)d_out;
  char* ws = (char*)d_ws;
  int* counts = (int*)ws;
  float* lossparts = (float*)(ws + 8192);
  double* normsq = (double*)(ws + 16384);
  int* idx = (int*)(ws + 32768);
  _Float16* Et = (_Float16*)(ws + 163840);

  hipMemsetAsync(ws, 0, 32768, stream);  // counts + lossparts + normsq
  k_norm<<<64, 256, 0, stream>>>(E, normsq);
  k_convE<<<256, 256, 0, stream>>>(E, normsq, Et);
  k_score<<<NN / 32, 256, 0, stream>>>(x, Et, idx, out + 8388611, counts);
  k_quant<<<(NN * DN / 4) / 256, 256, 0, stream>>>(x, E, idx, out, lossparts);
  k_final<<<1, 256, 0, stream>>>(counts, lossparts, out);
}